// Round 1
// baseline (389.609 us; speedup 1.0000x reference)
//
#include <hip/hip_runtime.h>

// VectorQuantizer: N=65536 encodings (fp32, D=128), K=1024 codebook entries.
// scores = -2*E@C^T + ||c||^2 ; argmin over k ; gather ; mse losses.
// Identities used:
//   commitment_loss == embedding_loss == mse = sum_r(||e_r||^2 + minscore_r)/(N*D)
//   vq_loss = mse*BETA + mse = 1.25*mse   (BETA = 0.25)
//   quantized_st == codebook[argmin]  (forward value of straight-through)
// Output layout (flat fp32): [0,N) index-as-float | [N, N+N*D) quantized_st |
//   [N+N*D + {0,1,2}] = vq_loss, embedding_loss, commitment_loss.

#define NROWS 65536
#define KCB   1024
#define DIM   128
#define DV    32          // float4 per row (DIM/4)
#define BM    64          // rows per block
#define BKC   64          // codewords per K-chunk
#define NCHUNK (KCB / BKC)
#define MSE_DENOM 8388608.0f   // N*D

// ---------------- prep: cnorm + zero loss accumulator ----------------
__global__ __launch_bounds__(256) void vq_prep(const float* __restrict__ C,
                                               float* __restrict__ ws) {
  int k = blockIdx.x * 256 + threadIdx.x;   // grid 4x256 == KCB exactly
  if (k == 0) ws[0] = 0.0f;                 // loss accumulator
  const float4* c4 = (const float4*)C + (size_t)k * DV;
  float s = 0.f;
#pragma unroll 8
  for (int i = 0; i < DV; ++i) {
    float4 v = c4[i];
    s = fmaf(v.x, v.x, s); s = fmaf(v.y, v.y, s);
    s = fmaf(v.z, v.z, s); s = fmaf(v.w, v.w, s);
  }
  ws[64 + k] = s;
}

// ---------------- main: GEMM + fused argmin/loss/gather ----------------
__global__ __launch_bounds__(256) void vq_main(const float* __restrict__ E,
                                               const float* __restrict__ C,
                                               const float* __restrict__ cnorm,
                                               float* __restrict__ out,
                                               float* __restrict__ lossacc) {
  // 64KB LDS total: Es 64x128 fp32 (swizzled) + Cs 64x128 fp32 (swizzled).
  __shared__ float smem[16384];
  float4* EsV = (float4*)smem;            // 2048 float4
  float4* CsV = (float4*)(smem + 8192);   // 2048 float4

  const int tid  = threadIdx.x;
  const int row0 = blockIdx.x * BM;

  // stage E tile once (XOR-swizzle on float4 index so later reads are conflict-free)
#pragma unroll
  for (int i = 0; i < 8; ++i) {
    int flat = i * 256 + tid;
    int r = flat >> 5, d4 = flat & 31;
    EsV[r * 32 + (d4 ^ (r & 31))] = ((const float4*)E)[(size_t)(row0 + r) * DV + d4];
  }

  const int tx = tid & 15;   // col-thread: cols k = j*16 + tx
  const int ty = tid >> 4;   // row-thread: rows r = i*16 + ty

  int rbase[4], rmask[4];
#pragma unroll
  for (int i = 0; i < 4; ++i) { int r = i * 16 + ty; rbase[i] = r * 32; rmask[i] = r & 31; }

  float bestv[4]; int besti[4];
#pragma unroll
  for (int i = 0; i < 4; ++i) { bestv[i] = 3.0e38f; besti[i] = 0; }

  for (int ch = 0; ch < NCHUNK; ++ch) {
    const int k0 = ch * BKC;
    __syncthreads();   // protects Cs reuse (and Es staging on first iter)
#pragma unroll
    for (int i = 0; i < 8; ++i) {
      int flat = i * 256 + tid;
      int k = flat >> 5, d4 = flat & 31;
      CsV[k * 32 + (d4 ^ (k & 31))] = ((const float4*)C)[(size_t)(k0 + k) * DV + d4];
    }
    __syncthreads();

    float acc[4][4] = {};
#pragma unroll 8
    for (int d4 = 0; d4 < DV; ++d4) {
      float4 a[4], b[4];
#pragma unroll
      for (int i = 0; i < 4; ++i) a[i] = EsV[rbase[i] + (d4 ^ rmask[i])];
#pragma unroll
      for (int j = 0; j < 4; ++j) { int k = j * 16 + tx; b[j] = CsV[k * 32 + (d4 ^ (k & 31))]; }
#pragma unroll
      for (int i = 0; i < 4; ++i)
#pragma unroll
        for (int j = 0; j < 4; ++j) {
          acc[i][j] = fmaf(a[i].x, b[j].x, acc[i][j]);
          acc[i][j] = fmaf(a[i].y, b[j].y, acc[i][j]);
          acc[i][j] = fmaf(a[i].z, b[j].z, acc[i][j]);
          acc[i][j] = fmaf(a[i].w, b[j].w, acc[i][j]);
        }
    }

    // fold into running argmin (tie-break: lowest index, matching jnp.argmin)
#pragma unroll
    for (int j = 0; j < 4; ++j) {
      int kg = k0 + j * 16 + tx;
      float cn = cnorm[kg];
#pragma unroll
      for (int i = 0; i < 4; ++i) {
        float s = fmaf(-2.0f, acc[i][j], cn);
        if (s < bestv[i] || (s == bestv[i] && kg < besti[i])) { bestv[i] = s; besti[i] = kg; }
      }
    }
  }

  // cross-thread (tx) argmin reduction; alias onto Cs region
  float* Rv = smem + 8192;
  int*   Ri = (int*)(smem + 9216);
  int*   BI = (int*)(smem + 10240);
  __syncthreads();
#pragma unroll
  for (int i = 0; i < 4; ++i) {
    int r = i * 16 + ty;
    Rv[r * 16 + tx] = bestv[i];
    Ri[r * 16 + tx] = besti[i];
  }
  __syncthreads();

  if (tid < BM) {   // wave 0 exactly
    const int r = tid;
    float bv = Rv[r * 16]; int bi = Ri[r * 16];
#pragma unroll
    for (int t = 1; t < 16; ++t) {
      float v = Rv[r * 16 + t]; int ii = Ri[r * 16 + t];
      if (v < bv || (v == bv && ii < bi)) { bv = v; bi = ii; }
    }
    // ||e_r||^2 from the still-resident Es tile
    float en = 0.f;
#pragma unroll 8
    for (int d4 = 0; d4 < DV; ++d4) {
      float4 v = EsV[r * 32 + (d4 ^ (r & 31))];
      en = fmaf(v.x, v.x, en); en = fmaf(v.y, v.y, en);
      en = fmaf(v.z, v.z, en); en = fmaf(v.w, v.w, en);
    }
    out[row0 + r] = (float)bi;
    BI[r] = bi;
    float blocksum = en + bv;   // ||e - c_best||^2 for this row
#pragma unroll
    for (int off = 32; off > 0; off >>= 1) blocksum += __shfl_down(blocksum, off);
    if (tid == 0) atomicAdd(lossacc, blocksum);
  }
  __syncthreads();

  // quantized_st: gather chosen codewords (codebook is L2-resident, 512 KB)
  const float4* C4   = (const float4*)C;
  float4*       out4 = (float4*)out;    // out+NROWS is 16B-aligned (65536%4==0)
  for (int flat = tid; flat < BM * DV; flat += 256) {
    int r = flat >> 5, d4 = flat & 31;
    int k = BI[r];
    out4[(NROWS / 4) + (size_t)(row0 + r) * DV + d4] = C4[(size_t)k * DV + d4];
  }
}

// ---------------- final: scalar losses ----------------
__global__ void vq_final(const float* __restrict__ ws, float* __restrict__ out) {
  if (threadIdx.x == 0 && blockIdx.x == 0) {
    float mse = ws[0] / MSE_DENOM;
    out[NROWS + NROWS * DIM + 0] = 1.25f * mse;  // vq = 0.25*commit + embed
    out[NROWS + NROWS * DIM + 1] = mse;          // embedding_loss
    out[NROWS + NROWS * DIM + 2] = mse;          // commitment_loss
  }
}

extern "C" void kernel_launch(void* const* d_in, const int* in_sizes, int n_in,
                              void* d_out, int out_size, void* d_ws, size_t ws_size,
                              hipStream_t stream) {
  const float* E = (const float*)d_in[0];   // encoding  (65536 x 128)
  const float* C = (const float*)d_in[1];   // codebook  (1024 x 128)
  float* out = (float*)d_out;
  float* wsf = (float*)d_ws;                // [0]=loss acc, [64..64+1024)=cnorm

  vq_prep<<<KCB / 256, 256, 0, stream>>>(C, wsf);
  vq_main<<<NROWS / BM, 256, 0, stream>>>(E, C, wsf + 64, out, wsf);
  vq_final<<<1, 64, 0, stream>>>(wsf, out);
}

// Round 2
// 206.526 us; speedup vs baseline: 1.8865x; 1.8865x over previous
//
#include <hip/hip_runtime.h>

// VectorQuantizer, split-bf16 MFMA version.
// scores = -2*E@C^T + ||c||^2; argmin_k; gather; mse losses.
//   -2e = ehi + elo (bf16 RNE split), c = chi + clo
//   -2*dot(e,c) ~= (ehi+elo)@chi + ehi@clo   (drop elo@clo, err ~1e-7..3e-6)
// MFMA D[m=codeword][n=enc_row] so each lane folds scores for ONE enc row.
// Rows whose top-2 gap < MARGIN get an exact fp32 rescan (vq_fix).
// Output: [0,N) idx as float | [N,N+N*D) quantized | +0,1,2 = vq,embed,commit.

#define NROWS 65536
#define KCB   1024
#define DIM   128
#define DV    32
#define MSE_DENOM 8388608.0f
#define MARGIN 3.0e-5f
#define FLAGCAP 16384

// ws byte layout (new path)
#define WS_CNORM_F 256      // float index: cnorm[1024] at byte 1024
#define WS_LIST_B  8192     // 16384 ints
#define WS_PH_B    73728    // 262144 B packed codebook hi frags
#define WS_PL_B    335872   // 262144 B packed codebook lo frags
#define WS_NEEDED  598016

typedef __attribute__((ext_vector_type(8)))  short short8;
typedef __attribute__((ext_vector_type(16))) float float16v;
union U4S8 { uint4 u; short8 s; };
union F4A  { float4 v; float f[4]; };

__device__ __forceinline__ unsigned bf16rne(float x) {
  unsigned u = __float_as_uint(x);
  return (u + 0x7FFFu + ((u >> 16) & 1u)) >> 16;
}
__device__ __forceinline__ void split2(float y, unsigned& hb, unsigned& lb) {
  hb = bf16rne(y);
  float hf = __uint_as_float(hb << 16);
  lb = bf16rne(y - hf);
}
__device__ __forceinline__ unsigned umn(unsigned a, unsigned b) { return a < b ? a : b; }
__device__ __forceinline__ unsigned umx(unsigned a, unsigned b) { return a > b ? a : b; }
__device__ __forceinline__ float unmap_score(unsigned up) {
  return (up & 0x80000000u) ? __uint_as_float(up ^ 0x80000000u) : __uint_as_float(~up);
}

// ---------- prep0: cnorm + zero loss/nflag ----------
__global__ __launch_bounds__(256) void vq_prep0(const float* __restrict__ C,
                                                float* __restrict__ wsf) {
  int k = blockIdx.x * 256 + threadIdx.x;   // grid 4x256 == 1024
  if (k == 0) { wsf[0] = 0.0f; ((unsigned*)wsf)[1] = 0u; }
  const float4* c4 = (const float4*)C + (size_t)k * DV;
  float s = 0.f;
#pragma unroll 8
  for (int i = 0; i < DV; ++i) {
    float4 v = c4[i];
    s = fmaf(v.x, v.x, s); s = fmaf(v.y, v.y, s);
    s = fmaf(v.z, v.z, s); s = fmaf(v.w, v.w, s);
  }
  wsf[WS_CNORM_F + k] = s;
}

// ---------- pack codebook into frag-linear hi/lo bf16 ----------
// slot g in [0,16384): mt=g>>9, s=(g>>6)&7, l=g&63
// value j: C[mt*32+(l&31)][s*16+(l>>5)*8+j]
__global__ __launch_bounds__(256) void vq_pack(const float* __restrict__ C,
                                               uint4* __restrict__ PH,
                                               uint4* __restrict__ PL) {
  int g = blockIdx.x * 256 + threadIdx.x;   // grid 64x256
  int mt = g >> 9, s = (g >> 6) & 7, l = g & 63;
  int cw = mt * 32 + (l & 31);
  int k0 = s * 16 + (l >> 5) * 8;
  const float* src = C + (size_t)cw * DIM + k0;
  float4 x0 = *(const float4*)src;
  float4 x1 = *(const float4*)(src + 4);
  unsigned h[8], lo[8];
  split2(x0.x, h[0], lo[0]); split2(x0.y, h[1], lo[1]);
  split2(x0.z, h[2], lo[2]); split2(x0.w, h[3], lo[3]);
  split2(x1.x, h[4], lo[4]); split2(x1.y, h[5], lo[5]);
  split2(x1.z, h[6], lo[6]); split2(x1.w, h[7], lo[7]);
  uint4 ph = make_uint4(h[0] | (h[1] << 16), h[2] | (h[3] << 16),
                        h[4] | (h[5] << 16), h[6] | (h[7] << 16));
  uint4 pl = make_uint4(lo[0] | (lo[1] << 16), lo[2] | (lo[3] << 16),
                        lo[4] | (lo[5] << 16), lo[6] | (lo[7] << 16));
  PH[g] = ph; PL[g] = pl;
}

// ---------- main: MFMA sweep + argmin + loss + gather ----------
__global__ __launch_bounds__(256, 2) void vq_main2(const float* __restrict__ E,
                                                   const float* __restrict__ C,
                                                   float* __restrict__ wsf,
                                                   float* __restrict__ out) {
  __shared__ uint4 EH[2048];          // 128 rows x 16 chunks, frag-linear
  __shared__ uint4 EL[2048];
  __shared__ float CN[1024];
  __shared__ float PART[256];         // [row][half] partial ||e||^2
  __shared__ uint2 M2[512];           // [wave][row] packed best/second
  __shared__ int   BI[128];

  const int tid  = threadIdx.x;
  const int w    = tid >> 6;          // wave 0..3
  const int l    = tid & 63;
  const int half = l >> 5;
  const int rr   = l & 31;
  const int row0 = blockIdx.x * 128;

  const uint4* PH = (const uint4*)((const char*)wsf + WS_PH_B);
  const uint4* PL = (const uint4*)((const char*)wsf + WS_PL_B);

  // ---- stage E tile: wave w stages rows w*32..w*32+31; lane covers one half-row ----
  {
    int r = w * 32 + rr;
    const float* eb = E + (size_t)(row0 + r) * DIM + half * 64;
    float s2 = 0.f;
#pragma unroll
    for (int i = 0; i < 8; ++i) {
      float4 x0 = *(const float4*)(eb + i * 8);
      float4 x1 = *(const float4*)(eb + i * 8 + 4);
      s2 = fmaf(x0.x, x0.x, s2); s2 = fmaf(x0.y, x0.y, s2);
      s2 = fmaf(x0.z, x0.z, s2); s2 = fmaf(x0.w, x0.w, s2);
      s2 = fmaf(x1.x, x1.x, s2); s2 = fmaf(x1.y, x1.y, s2);
      s2 = fmaf(x1.z, x1.z, s2); s2 = fmaf(x1.w, x1.w, s2);
      unsigned h[8], lo[8];
      split2(-2.f * x0.x, h[0], lo[0]); split2(-2.f * x0.y, h[1], lo[1]);
      split2(-2.f * x0.z, h[2], lo[2]); split2(-2.f * x0.w, h[3], lo[3]);
      split2(-2.f * x1.x, h[4], lo[4]); split2(-2.f * x1.y, h[5], lo[5]);
      split2(-2.f * x1.z, h[6], lo[6]); split2(-2.f * x1.w, h[7], lo[7]);
      int a16 = w * 512 + (half * 8 + i) * 32 + rr;   // frag-linear, contiguous per wave
      EH[a16] = make_uint4(h[0] | (h[1] << 16), h[2] | (h[3] << 16),
                           h[4] | (h[5] << 16), h[6] | (h[7] << 16));
      EL[a16] = make_uint4(lo[0] | (lo[1] << 16), lo[2] | (lo[3] << 16),
                           lo[4] | (lo[5] << 16), lo[6] | (lo[7] << 16));
    }
    PART[r * 2 + half] = s2;
    ((float4*)CN)[tid] = ((const float4*)(wsf + WS_CNORM_F))[tid];
  }
  __syncthreads();

  // ---- sweep: wave w covers codeword tiles w*8 .. w*8+7, in 4 groups of 2 ----
  unsigned best[4], second[4];
#pragma unroll
  for (int n = 0; n < 4; ++n) { best[n] = 0xFFFFFFFFu; second[n] = 0xFFFFFFFFu; }

  for (int g = 0; g < 4; ++g) {
    const int mtA = w * 8 + g * 2;
    short8 ah[2][8], al[2][8];
#pragma unroll
    for (int t = 0; t < 2; ++t)
#pragma unroll
      for (int s = 0; s < 8; ++s) {
        U4S8 ch, cl;
        ch.u = PH[(size_t)((mtA + t) * 8 + s) * 64 + l];
        cl.u = PL[(size_t)((mtA + t) * 8 + s) * 64 + l];
        ah[t][s] = ch.s; al[t][s] = cl.s;
      }
    float cnv[2][16];
#pragma unroll
    for (int t = 0; t < 2; ++t)
#pragma unroll
      for (int q = 0; q < 4; ++q) {
        F4A a; a.v = *(const float4*)&CN[(mtA + t) * 32 + q * 8 + half * 4];
#pragma unroll
        for (int i = 0; i < 4; ++i) cnv[t][q * 4 + i] = a.f[i];
      }

#pragma unroll
    for (int n = 0; n < 4; ++n) {
      float16v acc0 = {0,0,0,0,0,0,0,0,0,0,0,0,0,0,0,0};
      float16v acc1 = {0,0,0,0,0,0,0,0,0,0,0,0,0,0,0,0};
#pragma unroll
      for (int s = 0; s < 8; ++s) {
        U4S8 bh, bl;
        bh.u = EH[n * 512 + (s * 2 + half) * 32 + rr];
        bl.u = EL[n * 512 + (s * 2 + half) * 32 + rr];
        acc0 = __builtin_amdgcn_mfma_f32_32x32x16_bf16(ah[0][s], bh.s, acc0, 0, 0, 0);
        acc1 = __builtin_amdgcn_mfma_f32_32x32x16_bf16(ah[1][s], bh.s, acc1, 0, 0, 0);
        acc0 = __builtin_amdgcn_mfma_f32_32x32x16_bf16(al[0][s], bh.s, acc0, 0, 0, 0);
        acc1 = __builtin_amdgcn_mfma_f32_32x32x16_bf16(al[1][s], bh.s, acc1, 0, 0, 0);
        acc0 = __builtin_amdgcn_mfma_f32_32x32x16_bf16(ah[0][s], bl.s, acc0, 0, 0, 0);
        acc1 = __builtin_amdgcn_mfma_f32_32x32x16_bf16(ah[1][s], bl.s, acc1, 0, 0, 0);
      }
      const unsigned cwb0 = (unsigned)((mtA + 0) * 32 + half * 4);
      const unsigned cwb1 = (unsigned)((mtA + 1) * 32 + half * 4);
#pragma unroll
      for (int reg = 0; reg < 16; ++reg) {
        int q = reg >> 2, i = reg & 3;
        {
          float sc = acc0[reg] + cnv[0][reg];
          unsigned u = __float_as_uint(sc);
          u ^= ((unsigned)(((int)u) >> 31)) | 0x80000000u;
          u = (u & 0xFFFFFC00u) | (cwb0 + (unsigned)(q * 8 + i));
          unsigned nb = umn(best[n], u);
          second[n] = umn(second[n], umx(best[n], u));
          best[n] = nb;
        }
        {
          float sc = acc1[reg] + cnv[1][reg];
          unsigned u = __float_as_uint(sc);
          u ^= ((unsigned)(((int)u) >> 31)) | 0x80000000u;
          u = (u & 0xFFFFFC00u) | (cwb1 + (unsigned)(q * 8 + i));
          unsigned nb = umn(best[n], u);
          second[n] = umn(second[n], umx(best[n], u));
          best[n] = nb;
        }
      }
    }
  }

  // ---- merge halves, stash per-wave results ----
#pragma unroll
  for (int n = 0; n < 4; ++n) {
    unsigned b = best[n], s = second[n];
    unsigned ob = (unsigned)__shfl_xor((int)b, 32, 64);
    unsigned os = (unsigned)__shfl_xor((int)s, 32, 64);
    unsigned nb = umn(b, ob);
    unsigned ns = umn(umn(s, os), umx(b, ob));
    if (half == 0) M2[w * 128 + n * 32 + rr] = make_uint2(nb, ns);
  }
  __syncthreads();

  // ---- final per-row: merge 4 waves, unpack, flag, loss, index ----
  if (tid < 128) {
    const int r = tid;
    uint2 p0 = M2[r];
    unsigned b = p0.x, s = p0.y;
#pragma unroll
    for (int ww = 1; ww < 4; ++ww) {
      uint2 p = M2[ww * 128 + r];
      s = umn(umn(s, p.y), umx(b, p.x));
      b = umn(b, p.x);
    }
    int   bi = (int)(b & 1023u);
    float bv = unmap_score(b & 0xFFFFFC00u);
    float sv = unmap_score(s & 0xFFFFFC00u);
    out[row0 + r] = (float)bi;
    BI[r] = bi;
    if (sv - bv < MARGIN) {
      unsigned idx = atomicAdd((unsigned*)wsf + 1, 1u);
      if (idx < FLAGCAP) ((int*)((char*)wsf + WS_LIST_B))[idx] = row0 + r;
    }
    float term = PART[r * 2] + PART[r * 2 + 1] + bv;
#pragma unroll
    for (int off = 32; off > 0; off >>= 1) term += __shfl_down(term, off);
    if ((tid & 63) == 0) atomicAdd(wsf, term);
  }
  __syncthreads();

  // ---- gather quantized_st ----
  const float4* C4   = (const float4*)C;
  float4*       out4 = (float4*)out;
#pragma unroll
  for (int it = 0; it < 16; ++it) {
    int flat = it * 256 + tid;
    int r = flat >> 5, d4 = flat & 31;
    out4[(NROWS / 4) + (size_t)(row0 + r) * DV + d4] = C4[(size_t)BI[r] * DV + d4];
  }
}

// ---------- exact fp32 rescan of flagged rows (2 rows per sweep) ----------
__global__ __launch_bounds__(256) void vq_fix(const float* __restrict__ E,
                                              const float* __restrict__ C,
                                              float* __restrict__ wsf,
                                              float* __restrict__ out) {
  __shared__ float4 eL0[32], eL1[32];
  __shared__ float  sv0[256], sv1[256];
  __shared__ int    si0[256], si1[256];
  __shared__ int    RESi[2];
  const int tid = threadIdx.x;
  const int* list = (const int*)((const char*)wsf + WS_LIST_B);
  int nf = (int)((const unsigned*)wsf)[1];
  if (nf > FLAGCAP) nf = FLAGCAP;
  const float4* E4 = (const float4*)E;
  const float4* C4 = (const float4*)C;
  const float*  cn = wsf + WS_CNORM_F;
  float4* out4 = (float4*)out;

  for (int pair = blockIdx.x; pair * 2 < nf; pair += gridDim.x) {
    const int r0 = list[pair * 2];
    const int r1 = (pair * 2 + 1 < nf) ? list[pair * 2 + 1] : r0;
    if (tid < 32) eL0[tid] = E4[(size_t)r0 * DV + tid];
    else if (tid < 64) eL1[tid - 32] = E4[(size_t)r1 * DV + (tid - 32)];
    __syncthreads();
    float bv0 = 3.0e38f, bv1 = 3.0e38f; int bi0 = 0, bi1 = 0;
#pragma unroll
    for (int j = 0; j < 4; ++j) {
      int k = j * 256 + tid;
      float d0 = 0.f, d1 = 0.f;
#pragma unroll 8
      for (int d4 = 0; d4 < 32; ++d4) {
        float4 c = C4[(size_t)k * DV + d4];
        float4 e0 = eL0[d4], e1 = eL1[d4];
        d0 = fmaf(c.x, e0.x, d0); d0 = fmaf(c.y, e0.y, d0);
        d0 = fmaf(c.z, e0.z, d0); d0 = fmaf(c.w, e0.w, d0);
        d1 = fmaf(c.x, e1.x, d1); d1 = fmaf(c.y, e1.y, d1);
        d1 = fmaf(c.z, e1.z, d1); d1 = fmaf(c.w, e1.w, d1);
      }
      float s0 = fmaf(-2.f, d0, cn[k]);
      float s1 = fmaf(-2.f, d1, cn[k]);
      if (s0 < bv0 || (s0 == bv0 && k < bi0)) { bv0 = s0; bi0 = k; }
      if (s1 < bv1 || (s1 == bv1 && k < bi1)) { bv1 = s1; bi1 = k; }
    }
    sv0[tid] = bv0; si0[tid] = bi0; sv1[tid] = bv1; si1[tid] = bi1;
    __syncthreads();
    if (tid < 64) {
      float v0 = sv0[tid]; int i0 = si0[tid];
      float v1 = sv1[tid]; int i1 = si1[tid];
#pragma unroll
      for (int q = 1; q < 4; ++q) {
        float w0 = sv0[tid + q * 64]; int j0 = si0[tid + q * 64];
        float w1 = sv1[tid + q * 64]; int j1 = si1[tid + q * 64];
        if (w0 < v0 || (w0 == v0 && j0 < i0)) { v0 = w0; i0 = j0; }
        if (w1 < v1 || (w1 == v1 && j1 < i1)) { v1 = w1; i1 = j1; }
      }
#pragma unroll
      for (int off = 32; off > 0; off >>= 1) {
        float w0 = __shfl_down(v0, off); int j0 = __shfl_down(i0, off);
        float w1 = __shfl_down(v1, off); int j1 = __shfl_down(i1, off);
        if (w0 < v0 || (w0 == v0 && j0 < i0)) { v0 = w0; i0 = j0; }
        if (w1 < v1 || (w1 == v1 && j1 < i1)) { v1 = w1; i1 = j1; }
      }
      if (tid == 0) {
        RESi[0] = i0; RESi[1] = i1;
        out[r0] = (float)i0; out[r1] = (float)i1;
      }
    }
    __syncthreads();
    if (tid < 32) out4[(NROWS / 4) + (size_t)r0 * DV + tid] = C4[(size_t)RESi[0] * DV + tid];
    else if (tid < 64) out4[(NROWS / 4) + (size_t)r1 * DV + (tid - 32)] = C4[(size_t)RESi[1] * DV + (tid - 32)];
    __syncthreads();
  }
}

// ---------- final scalars ----------
__global__ void vq_final(const float* __restrict__ wsf, float* __restrict__ out) {
  if (threadIdx.x == 0 && blockIdx.x == 0) {
    float mse = wsf[0] / MSE_DENOM;
    out[NROWS + NROWS * DIM + 0] = 1.25f * mse;
    out[NROWS + NROWS * DIM + 1] = mse;
    out[NROWS + NROWS * DIM + 2] = mse;
  }
}

// ================= fallback (round-1 fp32 path, used if ws too small) ==========
__global__ __launch_bounds__(256) void vq_prep_fb(const float* __restrict__ C,
                                                  float* __restrict__ ws) {
  int k = blockIdx.x * 256 + threadIdx.x;
  if (k == 0) ws[0] = 0.0f;
  const float4* c4 = (const float4*)C + (size_t)k * DV;
  float s = 0.f;
#pragma unroll 8
  for (int i = 0; i < DV; ++i) {
    float4 v = c4[i];
    s = fmaf(v.x, v.x, s); s = fmaf(v.y, v.y, s);
    s = fmaf(v.z, v.z, s); s = fmaf(v.w, v.w, s);
  }
  ws[64 + k] = s;
}

__global__ __launch_bounds__(256) void vq_main_fb(const float* __restrict__ E,
                                                  const float* __restrict__ C,
                                                  const float* __restrict__ cnorm,
                                                  float* __restrict__ out,
                                                  float* __restrict__ lossacc) {
  __shared__ float smem[16384];
  float4* EsV = (float4*)smem;
  float4* CsV = (float4*)(smem + 8192);
  const int tid  = threadIdx.x;
  const int row0 = blockIdx.x * 64;
#pragma unroll
  for (int i = 0; i < 8; ++i) {
    int flat = i * 256 + tid;
    int r = flat >> 5, d4 = flat & 31;
    EsV[r * 32 + (d4 ^ (r & 31))] = ((const float4*)E)[(size_t)(row0 + r) * DV + d4];
  }
  const int tx = tid & 15, ty = tid >> 4;
  int rbase[4], rmask[4];
#pragma unroll
  for (int i = 0; i < 4; ++i) { int r = i * 16 + ty; rbase[i] = r * 32; rmask[i] = r & 31; }
  float bestv[4]; int besti[4];
#pragma unroll
  for (int i = 0; i < 4; ++i) { bestv[i] = 3.0e38f; besti[i] = 0; }
  for (int ch = 0; ch < 16; ++ch) {
    const int k0 = ch * 64;
    __syncthreads();
#pragma unroll
    for (int i = 0; i < 8; ++i) {
      int flat = i * 256 + tid;
      int k = flat >> 5, d4 = flat & 31;
      CsV[k * 32 + (d4 ^ (k & 31))] = ((const float4*)C)[(size_t)(k0 + k) * DV + d4];
    }
    __syncthreads();
    float acc[4][4] = {};
#pragma unroll 8
    for (int d4 = 0; d4 < DV; ++d4) {
      float4 a[4], b[4];
#pragma unroll
      for (int i = 0; i < 4; ++i) a[i] = EsV[rbase[i] + (d4 ^ rmask[i])];
#pragma unroll
      for (int j = 0; j < 4; ++j) { int k = j * 16 + tx; b[j] = CsV[k * 32 + (d4 ^ (k & 31))]; }
#pragma unroll
      for (int i = 0; i < 4; ++i)
#pragma unroll
        for (int j = 0; j < 4; ++j) {
          acc[i][j] = fmaf(a[i].x, b[j].x, acc[i][j]);
          acc[i][j] = fmaf(a[i].y, b[j].y, acc[i][j]);
          acc[i][j] = fmaf(a[i].z, b[j].z, acc[i][j]);
          acc[i][j] = fmaf(a[i].w, b[j].w, acc[i][j]);
        }
    }
#pragma unroll
    for (int j = 0; j < 4; ++j) {
      int kg = k0 + j * 16 + tx;
      float cnv = cnorm[kg];
#pragma unroll
      for (int i = 0; i < 4; ++i) {
        float s = fmaf(-2.0f, acc[i][j], cnv);
        if (s < bestv[i] || (s == bestv[i] && kg < besti[i])) { bestv[i] = s; besti[i] = kg; }
      }
    }
  }
  float* Rv = smem + 8192;
  int*   Ri = (int*)(smem + 9216);
  int*   BIf = (int*)(smem + 10240);
  __syncthreads();
#pragma unroll
  for (int i = 0; i < 4; ++i) {
    int r = i * 16 + ty;
    Rv[r * 16 + tx] = bestv[i];
    Ri[r * 16 + tx] = besti[i];
  }
  __syncthreads();
  if (tid < 64) {
    const int r = tid;
    float bv = Rv[r * 16]; int bi = Ri[r * 16];
#pragma unroll
    for (int t = 1; t < 16; ++t) {
      float v = Rv[r * 16 + t]; int ii = Ri[r * 16 + t];
      if (v < bv || (v == bv && ii < bi)) { bv = v; bi = ii; }
    }
    float en = 0.f;
#pragma unroll 8
    for (int d4 = 0; d4 < DV; ++d4) {
      float4 v = EsV[r * 32 + (d4 ^ (r & 31))];
      en = fmaf(v.x, v.x, en); en = fmaf(v.y, v.y, en);
      en = fmaf(v.z, v.z, en); en = fmaf(v.w, v.w, en);
    }
    out[row0 + r] = (float)bi;
    BIf[r] = bi;
    float blocksum = en + bv;
#pragma unroll
    for (int off = 32; off > 0; off >>= 1) blocksum += __shfl_down(blocksum, off);
    if (tid == 0) atomicAdd(lossacc, blocksum);
  }
  __syncthreads();
  const float4* C4   = (const float4*)C;
  float4*       out4 = (float4*)out;
  for (int flat = tid; flat < 64 * DV; flat += 256) {
    int r = flat >> 5, d4 = flat & 31;
    out4[(NROWS / 4) + (size_t)(row0 + r) * DV + d4] = C4[(size_t)BIf[r] * DV + d4];
  }
}

__global__ void vq_final_fb(const float* __restrict__ ws, float* __restrict__ out) {
  if (threadIdx.x == 0 && blockIdx.x == 0) {
    float mse = ws[0] / MSE_DENOM;
    out[NROWS + NROWS * DIM + 0] = 1.25f * mse;
    out[NROWS + NROWS * DIM + 1] = mse;
    out[NROWS + NROWS * DIM + 2] = mse;
  }
}

extern "C" void kernel_launch(void* const* d_in, const int* in_sizes, int n_in,
                              void* d_out, int out_size, void* d_ws, size_t ws_size,
                              hipStream_t stream) {
  const float* E = (const float*)d_in[0];
  const float* C = (const float*)d_in[1];
  float* out = (float*)d_out;
  float* wsf = (float*)d_ws;

  if (ws_size >= (size_t)WS_NEEDED) {
    uint4* PH = (uint4*)((char*)d_ws + WS_PH_B);
    uint4* PL = (uint4*)((char*)d_ws + WS_PL_B);
    vq_prep0<<<4, 256, 0, stream>>>(C, wsf);
    vq_pack<<<64, 256, 0, stream>>>(C, PH, PL);
    vq_main2<<<NROWS / 128, 256, 0, stream>>>(E, C, wsf, out);
    vq_fix<<<256, 256, 0, stream>>>(E, C, wsf, out);
    vq_final<<<1, 64, 0, stream>>>(wsf, out);
  } else {
    vq_prep_fb<<<4, 256, 0, stream>>>(C, wsf);
    vq_main_fb<<<NROWS / 64, 256, 0, stream>>>(E, C, wsf + 64, out, wsf);
    vq_final_fb<<<1, 64, 0, stream>>>(wsf, out);
  }
}